// Round 5
// baseline (504.060 us; speedup 1.0000x reference)
//
#include <hip/hip_runtime.h>
#include <hip/hip_bf16.h>
#include <float.h>
#include <math.h>

#define KEY_DIM   512
#define VALUE_DIM 128
#define CAPACITY  500000
#define NRET      16

#define TILE_ROWS 16
#define NBLKS     2048
#define NTILES_TOT (CAPACITY / TILE_ROWS)   // 31250

#define AS3 __attribute__((address_space(3)))
#define AS1 __attribute__((address_space(1)))

__device__ __forceinline__ float wave_sum(float x) {
#pragma unroll
    for (int s = 32; s > 0; s >>= 1) x += __shfl_xor(x, s);
    return x;
}

// ---------------- Kernel 1a/1b: y[r] = act(dot(W[r,:], x) + b[r]) ----------
template <bool SILU>
__global__ __launch_bounds__(256) void matvec512(
        const float* __restrict__ W, const float* __restrict__ x,
        const float* __restrict__ b, float* __restrict__ y) {
    const int wid  = threadIdx.x >> 6;
    const int lane = threadIdx.x & 63;
    const int r = blockIdx.x * 4 + wid;          // 0..511

    const float4* Wr = (const float4*)(W + (size_t)r * KEY_DIM);
    const float4* xv = (const float4*)x;

    float4 w0 = Wr[lane], w1 = Wr[lane + 64];
    float4 x0 = xv[lane], x1 = xv[lane + 64];

    float dot = w0.x * x0.x + w0.y * x0.y + w0.z * x0.z + w0.w * x0.w
              + w1.x * x1.x + w1.y * x1.y + w1.z * x1.z + w1.w * x1.w;
    dot = wave_sum(dot);

    if (lane == 0) {
        float v = dot + b[r];
        if (SILU) v = v / (1.0f + expf(-v));     // silu = x*sigmoid(x)
        y[r] = v;
    }
}

// ---------------- Kernel 1c: LayerNorm + l2-normalize -> qn[512] -----------
__global__ __launch_bounds__(512) void ln_l2norm(
        const float* __restrict__ h, const float* __restrict__ gamma,
        const float* __restrict__ beta, float* __restrict__ qn) {
    __shared__ float s1[8], s2[8];
    const int t = threadIdx.x;                   // 512 threads = 8 waves
    const int wid = t >> 6, lane = t & 63;

    float x = h[t];
    float a = x, bb = x * x;
#pragma unroll
    for (int s = 32; s > 0; s >>= 1) { a += __shfl_xor(a, s); bb += __shfl_xor(bb, s); }
    if (lane == 0) { s1[wid] = a; s2[wid] = bb; }
    __syncthreads();

    float suma = 0.f, sumb = 0.f;
#pragma unroll
    for (int i = 0; i < 8; ++i) { suma += s1[i]; sumb += s2[i]; }
    float mu  = suma * (1.0f / KEY_DIM);
    float var = sumb * (1.0f / KEY_DIM) - mu * mu;      // biased, like torch LN
    float ln  = (x - mu) / sqrtf(var + 1e-5f) * gamma[t] + beta[t];

    float c = wave_sum(ln * ln);
    __syncthreads();
    if (lane == 0) s1[wid] = c;
    __syncthreads();
    float ss = 0.f;
#pragma unroll
    for (int i = 0; i < 8; ++i) ss += s1[i];
    float n = fmaxf(sqrtf(ss), 1e-12f);
    qn[t] = ln / n;
}

// ---------------- Kernel 2: LDS-staged cosine sim + per-block top-16 -------
// Tile = 16 rows x 512 cols (32 KB), double-buffered via global_load_lds.
// Thread t owns row r = t&15, col-slice g = t>>4 (32 cols): 8 ds_read_b128 +
// 64 FMA per tile, NO cross-lane shuffles. Involution swizzle cell^=(row&7)
// applied on BOTH the global source (stage) and the LDS read.
// Partial (dot,ss) -> padded LDS -> wave0 reduces 16 rows, rare ballot insert.

__global__ __launch_bounds__(256) void sim_topk(
        const float* __restrict__ keys, const float* __restrict__ qn,
        float* __restrict__ cand_v, int* __restrict__ cand_i) {
    __shared__ float klds[2][TILE_ROWS * KEY_DIM];   // 2 x 32 KB
    __shared__ float pd[2][16][20];                  // +4 pad: bank spread
    __shared__ float ps[2][16][20];

    const int tid  = threadIdx.x;
    const int wid  = tid >> 6;
    const int lane = tid & 63;
    const int r    = tid & 15;                       // owned row in tile
    const int g    = tid >> 4;                       // col-slice 0..15 (32 cols)
    const int bid  = blockIdx.x;

    // q slice for this thread: cols [g*32, g*32+32) = cells g*8..g*8+7
    float4 qr[8];
    {
        const float4* q4 = (const float4*)qn;
#pragma unroll
        for (int i = 0; i < 8; ++i) qr[i] = q4[g * 8 + i];
    }

    // block top-16 (maintained wave-uniform by wave 0)
    float v[16]; int id[16];
#pragma unroll
    for (int j = 0; j < 16; ++j) { v[j] = -FLT_MAX; id[j] = 0x7fffffff; }

    // ---- staging helper (inlined by hand below via lambda) ----
    auto stage_tile = [&](int T, float* ldsbuf) {
#pragma unroll
        for (int j = 0; j < 8; ++j) {
            const int s    = wid * 8 + j;            // 0..31
            const int row  = s >> 1;                 // 0..15
            const int half = s & 1;
            const int cellp = half * 64 + lane;      // LDS cell' 0..127
            const int cell  = cellp ^ (row & 7);     // logical cell (involution)
            const float* gp = keys + ((size_t)T * TILE_ROWS + row) * KEY_DIM + cell * 4;
            float* lp = ldsbuf + s * 256;            // wave-uniform base (1 KB/instr)
            __builtin_amdgcn_global_load_lds((const AS1 float*)gp, (AS3 float*)lp,
                                             16, 0, 0);
        }
    };

    int t  = bid;
    int buf = 0, pb = 0;
    stage_tile(t, &klds[0][0]);
    __syncthreads();                                 // tile t staged

    for (;;) {
        const int tn = t + NBLKS;
        const bool more = (tn < NTILES_TOT);
        if (more) stage_tile(tn, &klds[buf ^ 1][0]); // prefetch next tile

        // ---- compute partial dot/ss from klds[buf] ----
        const float* Lr = &klds[buf][0] + r * KEY_DIM;
        float dot = 0.f, ss = 0.f;
#pragma unroll
        for (int i = 0; i < 8; ++i) {
            const int cp = (g * 8 + i) ^ (r & 7);    // swizzled cell
            float4 k = *(const float4*)(Lr + cp * 4);
            float4 q = qr[i];
            dot += k.x * q.x + k.y * q.y + k.z * q.z + k.w * q.w;
            ss  += k.x * k.x + k.y * k.y + k.z * k.z + k.w * k.w;
        }
        pd[pb][r][g] = dot;
        ps[pb][r][g] = ss;
        __syncthreads();                             // partials ready; stage(tn) landed

        // ---- wave 0: reduce 16 rows, insert into block top-16 ----
        if (wid == 0) {
            float sim = -FLT_MAX;
            if (lane < 16) {
                const float4* prd = (const float4*)&pd[pb][lane][0];
                const float4* prs = (const float4*)&ps[pb][lane][0];
                float4 d0 = prd[0], d1 = prd[1], d2 = prd[2], d3 = prd[3];
                float4 s0 = prs[0], s1 = prs[1], s2 = prs[2], s3 = prs[3];
                float d  = (d0.x + d0.y + d0.z + d0.w) + (d1.x + d1.y + d1.z + d1.w)
                         + (d2.x + d2.y + d2.z + d2.w) + (d3.x + d3.y + d3.z + d3.w);
                float sq = (s0.x + s0.y + s0.z + s0.w) + (s1.x + s1.y + s1.z + s1.w)
                         + (s2.x + s2.y + s2.z + s2.w) + (s3.x + s3.y + s3.z + s3.w);
                sim = d / fmaxf(sqrtf(sq), 1e-12f);
            }
            unsigned long long mball = __ballot(sim > v[15]);
            while (mball) {
                const int l = __ffsll(mball) - 1;
                mball &= mball - 1;
                float cv = __shfl(sim, l);
                int   ci = t * TILE_ROWS + l;
                if (cv > v[15]) {
#pragma unroll
                    for (int jj = 0; jj < 16; ++jj) {
                        if (cv > v[jj]) {
                            float tv = v[jj]; int ti = id[jj];
                            v[jj] = cv; id[jj] = ci; cv = tv; ci = ti;
                        }
                    }
                }
            }
        }

        pb ^= 1; buf ^= 1;
        if (!more) break;
        t = tn;
    }

    // ---- write block top-16 ----
    if (wid == 0 && lane == 0) {
#pragma unroll
        for (int j = 0; j < 16; ++j) {
            cand_v[bid * NRET + j] = v[j];
            cand_i[bid * NRET + j] = id[j];
        }
    }
}

// ---------------- Kernel 3: global top-16 + softmax + gather ---------------
__global__ __launch_bounds__(256) void merge_out(
        const float* __restrict__ cand_v, const int* __restrict__ cand_i,
        const float* __restrict__ values, float* __restrict__ out) {
    const int tid  = threadIdx.x;
    const int wid  = tid >> 6;
    const int lane = tid & 63;
    const int M4 = (NBLKS * NRET) / 4;           // 8192 float4 groups

    float v[16]; int id[16];
#pragma unroll
    for (int j = 0; j < 16; ++j) { v[j] = -FLT_MAX; id[j] = 0x7fffffff; }

    const float4* cv4 = (const float4*)cand_v;
    const int4*   ci4 = (const int4*)cand_i;
    for (int c = tid; c < M4; c += 256) {        // 32 iterations, vector loads
        float4 cv = cv4[c]; int4 ci = ci4[c];
        float cvs[4] = {cv.x, cv.y, cv.z, cv.w};
        int   cis[4] = {ci.x, ci.y, ci.z, ci.w};
#pragma unroll
        for (int u = 0; u < 4; ++u) {
            float cu = cvs[u]; int iu = cis[u];
            if (cu > v[15]) {
#pragma unroll
                for (int j = 0; j < 16; ++j) {
                    if (cu > v[j]) {
                        float tv = v[j]; int ti = id[j];
                        v[j] = cu; id[j] = iu; cu = tv; iu = ti;
                    }
                }
            }
        }
    }

    // per-wave argmax-pop of 16 winners -> LDS
    __shared__ float sv[64];
    __shared__ int   si[64];
    for (int rr = 0; rr < NRET; ++rr) {
        float mv = v[0]; int mi = id[0];
#pragma unroll
        for (int s = 32; s > 0; s >>= 1) {
            float ov = __shfl_xor(mv, s); int oi = __shfl_xor(mi, s);
            if (ov > mv || (ov == mv && oi < mi)) { mv = ov; mi = oi; }
        }
        if (v[0] == mv && id[0] == mi) {         // unique winner (unique indices)
#pragma unroll
            for (int j = 0; j < 15; ++j) { v[j] = v[j + 1]; id[j] = id[j + 1]; }
            v[15] = -FLT_MAX; id[15] = 0x7fffffff;
        }
        if (lane == 0) { sv[wid * 16 + rr] = mv; si[wid * 16 + rr] = mi; }
    }
    __syncthreads();

    if (wid == 0) {
        float lv = sv[lane]; int li = si[lane];
        float sel_v = -FLT_MAX; int sel_i = 0;
        for (int rr = 0; rr < NRET; ++rr) {
            float mv = lv; int mi = li;
#pragma unroll
            for (int s = 32; s > 0; s >>= 1) {
                float ov = __shfl_xor(mv, s); int oi = __shfl_xor(mi, s);
                if (ov > mv || (ov == mv && oi < mi)) { mv = ov; mi = oi; }
            }
            if (lv == mv && li == mi) { lv = -FLT_MAX; li = 0x7fffffff; }
            if (lane == rr) { sel_v = mv; sel_i = mi; }
        }

        // softmax over the 16 (lane 0 holds the max: rounds are descending)
        float m0 = __shfl(sel_v, 0);
        float e = (lane < NRET) ? expf(sel_v - m0) : 0.0f;
        float denom = wave_sum(e);

        float acc0 = 0.f, acc1 = 0.f;
        for (int rr = 0; rr < NRET; ++rr) {
            float ar = __shfl(e, rr) / denom;
            int   ir = __shfl(sel_i, rr);
            const float* vr = values + (size_t)ir * VALUE_DIM;
            acc0 += ar * vr[lane];
            acc1 += ar * vr[lane + 64];
        }
        out[lane]      = acc0;
        out[lane + 64] = acc1;
    }
}

extern "C" void kernel_launch(void* const* d_in, const int* in_sizes, int n_in,
                              void* d_out, int out_size, void* d_ws, size_t ws_size,
                              hipStream_t stream) {
    const float* query  = (const float*)d_in[0];
    const float* W1     = (const float*)d_in[1];
    const float* b1     = (const float*)d_in[2];
    const float* W2     = (const float*)d_in[3];
    const float* b2     = (const float*)d_in[4];
    const float* gamma  = (const float*)d_in[5];
    const float* beta   = (const float*)d_in[6];
    const float* keys   = (const float*)d_in[7];
    const float* values = (const float*)d_in[8];
    float* out = (float*)d_out;

    float* ws = (float*)d_ws;
    float* h1     = ws;                  // 512
    float* h2     = ws + 512;            // 512
    float* qn     = ws + 1024;           // 512
    float* cand_v = ws + 2048;           // NBLKS*16 floats (128 KB)
    int*   cand_i = (int*)(ws + 2048 + NBLKS * NRET);

    matvec512<true ><<<128, 256, 0, stream>>>(W1, query, b1, h1);
    matvec512<false><<<128, 256, 0, stream>>>(W2, h1, b2, h2);
    ln_l2norm<<<1, 512, 0, stream>>>(h2, gamma, beta, qn);
    sim_topk<<<NBLKS, 256, 0, stream>>>(keys, qn, cand_v, cand_i);
    merge_out<<<1, 256, 0, stream>>>(cand_v, cand_i, values, out);
}

// Round 6
// 365.247 us; speedup vs baseline: 1.3801x; 1.3801x over previous
//
#include <hip/hip_runtime.h>
#include <hip/hip_bf16.h>
#include <float.h>
#include <math.h>

#define KEY_DIM   512
#define VALUE_DIM 128
#define CAPACITY  500000
#define NRET      16

#define SIMBLKS   1954      // ceil(ceil(500000/64)/4) waves of 64 rows
#define TKBLKS    32        // phase-B stage-1 blocks

__device__ __forceinline__ float wave_sum(float x) {
#pragma unroll
    for (int s = 32; s > 0; s >>= 1) x += __shfl_xor(x, s);
    return x;
}

// ---------------- Kernel 1a/1b: y[r] = act(dot(W[r,:], x) + b[r]) ----------
template <bool SILU>
__global__ __launch_bounds__(256) void matvec512(
        const float* __restrict__ W, const float* __restrict__ x,
        const float* __restrict__ b, float* __restrict__ y) {
    const int wid  = threadIdx.x >> 6;
    const int lane = threadIdx.x & 63;
    const int r = blockIdx.x * 4 + wid;          // 0..511

    const float4* Wr = (const float4*)(W + (size_t)r * KEY_DIM);
    const float4* xv = (const float4*)x;

    float4 w0 = Wr[lane], w1 = Wr[lane + 64];
    float4 x0 = xv[lane], x1 = xv[lane + 64];

    float dot = w0.x * x0.x + w0.y * x0.y + w0.z * x0.z + w0.w * x0.w
              + w1.x * x1.x + w1.y * x1.y + w1.z * x1.z + w1.w * x1.w;
    dot = wave_sum(dot);

    if (lane == 0) {
        float v = dot + b[r];
        if (SILU) v = v / (1.0f + expf(-v));     // silu = x*sigmoid(x)
        y[r] = v;
    }
}

// ---------------- Kernel 1c: LayerNorm + l2-normalize -> qn[512] -----------
__global__ __launch_bounds__(512) void ln_l2norm(
        const float* __restrict__ h, const float* __restrict__ gamma,
        const float* __restrict__ beta, float* __restrict__ qn) {
    __shared__ float s1[8], s2[8];
    const int t = threadIdx.x;                   // 512 threads = 8 waves
    const int wid = t >> 6, lane = t & 63;

    float x = h[t];
    float a = x, bb = x * x;
#pragma unroll
    for (int s = 32; s > 0; s >>= 1) { a += __shfl_xor(a, s); bb += __shfl_xor(bb, s); }
    if (lane == 0) { s1[wid] = a; s2[wid] = bb; }
    __syncthreads();

    float suma = 0.f, sumb = 0.f;
#pragma unroll
    for (int i = 0; i < 8; ++i) { suma += s1[i]; sumb += s2[i]; }
    float mu  = suma * (1.0f / KEY_DIM);
    float var = sumb * (1.0f / KEY_DIM) - mu * mu;      // biased, like torch LN
    float ln  = (x - mu) / sqrtf(var + 1e-5f) * gamma[t] + beta[t];

    float c = wave_sum(ln * ln);
    __syncthreads();
    if (lane == 0) s1[wid] = c;
    __syncthreads();
    float ss = 0.f;
#pragma unroll
    for (int i = 0; i < 8; ++i) ss += s1[i];
    float n = fmaxf(sqrtf(ss), 1e-12f);
    qn[t] = ln / n;
}

// ---------------- Kernel 2: all cosine sims, lane = row, NO cross-lane -----
// Lane l of wave W owns row W*64+l. 16 chunks x 8 consecutive float4: the 8
// back-to-back loads per chunk cover each 128B line fully (MSHR-merged, 1x
// HBM traffic). q is broadcast from LDS (uniform ds_read = conflict-free).
// ~55 VGPR -> 8 waves/SIMD (32 waves/CU): TLP hides latency, like the copy
// bench. Sims written to global; selection deferred to phase B.
__global__ __launch_bounds__(256, 8) void sim_all(
        const float* __restrict__ keys, const float* __restrict__ qn,
        float* __restrict__ sims) {
    __shared__ float qs[KEY_DIM];
    const int tid = threadIdx.x;
    if (tid < 128) ((float4*)qs)[tid] = ((const float4*)qn)[tid];
    __syncthreads();

    const int wid  = tid >> 6;
    const int lane = tid & 63;
    const int W    = blockIdx.x * 4 + wid;
    const long row = (long)W * 64 + lane;
    if ((long)W * 64 >= CAPACITY) return;        // whole wave out of range

    const int rowc = (row < CAPACITY) ? (int)row : (CAPACITY - 1); // clamp loads
    const float4* kp = (const float4*)(keys + (size_t)rowc * KEY_DIM);
    const float4* qv = (const float4*)qs;

    float dot0 = 0.f, ss0 = 0.f, dot1 = 0.f, ss1 = 0.f;
#pragma unroll 1
    for (int c = 0; c < 16; ++c) {               // rolled: bounded VGPR
        float4 k[8];
#pragma unroll
        for (int j = 0; j < 8; ++j) k[j] = kp[c * 8 + j];
#pragma unroll
        for (int j = 0; j < 8; ++j) {
            float4 q = qv[c * 8 + j];
            if (j & 1) {
                dot1 += k[j].x * q.x + k[j].y * q.y + k[j].z * q.z + k[j].w * q.w;
                ss1  += k[j].x * k[j].x + k[j].y * k[j].y + k[j].z * k[j].z + k[j].w * k[j].w;
            } else {
                dot0 += k[j].x * q.x + k[j].y * q.y + k[j].z * q.z + k[j].w * q.w;
                ss0  += k[j].x * k[j].x + k[j].y * k[j].y + k[j].z * k[j].z + k[j].w * k[j].w;
            }
        }
    }
    float dot = dot0 + dot1;
    float ss  = ss0 + ss1;
    float sim = dot / fmaxf(sqrtf(ss), 1e-12f);
    if (row < CAPACITY) sims[row] = sim;
}

// ---------------- Kernel 3: stage-1 top-16 over sims -----------------------
// 32 blocks x 256 threads; thread scans ~61 sims (coalesced), private top-16,
// wave argmax-pop -> LDS -> wave0 pop -> 16 candidates per block.
__global__ __launch_bounds__(256) void topk_stage1(
        const float* __restrict__ sims,
        float* __restrict__ cand_v, int* __restrict__ cand_i) {
    const int tid  = threadIdx.x;
    const int wid  = tid >> 6;
    const int lane = tid & 63;
    const int bid  = blockIdx.x;
    const int STRIDE = TKBLKS * 256;             // 8192

    float v[16]; int id[16];
#pragma unroll
    for (int j = 0; j < 16; ++j) { v[j] = -FLT_MAX; id[j] = 0x7fffffff; }

    for (int k = 0; k < 62; ++k) {               // 62*8192 >= 500000
        const int idx = bid * 256 + tid + k * STRIDE;
        if (idx < CAPACITY) {
            float cv = sims[idx]; int ci = idx;
            if (cv > v[15]) {                    // per-lane predicated insert
#pragma unroll
                for (int j = 0; j < 16; ++j) {
                    if (cv > v[j]) {
                        float tv = v[j]; int ti = id[j];
                        v[j] = cv; id[j] = ci; cv = tv; ci = ti;
                    }
                }
            }
        }
    }

    __shared__ float sv[64];
    __shared__ int   si[64];
    for (int rr = 0; rr < NRET; ++rr) {          // per-wave argmax-pop
        float mv = v[0]; int mi = id[0];
#pragma unroll
        for (int s = 32; s > 0; s >>= 1) {
            float ov = __shfl_xor(mv, s); int oi = __shfl_xor(mi, s);
            if (ov > mv || (ov == mv && oi < mi)) { mv = ov; mi = oi; }
        }
        if (v[0] == mv && id[0] == mi) {         // unique winner (unique idx)
#pragma unroll
            for (int j = 0; j < 15; ++j) { v[j] = v[j + 1]; id[j] = id[j + 1]; }
            v[15] = -FLT_MAX; id[15] = 0x7fffffff;
        }
        if (lane == 0) { sv[wid * 16 + rr] = mv; si[wid * 16 + rr] = mi; }
    }
    __syncthreads();

    if (wid == 0) {                              // merge 4 waves -> block 16
        float lv = sv[lane]; int li = si[lane];
        for (int rr = 0; rr < NRET; ++rr) {
            float mv = lv; int mi = li;
#pragma unroll
            for (int s = 32; s > 0; s >>= 1) {
                float ov = __shfl_xor(mv, s); int oi = __shfl_xor(mi, s);
                if (ov > mv || (ov == mv && oi < mi)) { mv = ov; mi = oi; }
            }
            if (lane == 0) {
                cand_v[bid * NRET + rr] = mv;
                cand_i[bid * NRET + rr] = mi;
            }
            if (lv == mv && li == mi) { lv = -FLT_MAX; li = 0x7fffffff; }
        }
    }
}

// ---------------- Kernel 4: final top-16 + softmax + gather ----------------
__global__ __launch_bounds__(256) void merge_out(
        const float* __restrict__ cand_v, const int* __restrict__ cand_i,
        const float* __restrict__ values, float* __restrict__ out) {
    const int tid  = threadIdx.x;
    const int wid  = tid >> 6;
    const int lane = tid & 63;
    const int M4 = (TKBLKS * NRET) / 4;          // 128 float4 groups

    float v[16]; int id[16];
#pragma unroll
    for (int j = 0; j < 16; ++j) { v[j] = -FLT_MAX; id[j] = 0x7fffffff; }

    const float4* cv4 = (const float4*)cand_v;
    const int4*   ci4 = (const int4*)cand_i;
    for (int c = tid; c < M4; c += 256) {
        float4 cv = cv4[c]; int4 ci = ci4[c];
        float cvs[4] = {cv.x, cv.y, cv.z, cv.w};
        int   cis[4] = {ci.x, ci.y, ci.z, ci.w};
#pragma unroll
        for (int u = 0; u < 4; ++u) {
            float cu = cvs[u]; int iu = cis[u];
            if (cu > v[15]) {
#pragma unroll
                for (int j = 0; j < 16; ++j) {
                    if (cu > v[j]) {
                        float tv = v[j]; int ti = id[j];
                        v[j] = cu; id[j] = iu; cu = tv; iu = ti;
                    }
                }
            }
        }
    }

    __shared__ float sv[64];
    __shared__ int   si[64];
    for (int rr = 0; rr < NRET; ++rr) {
        float mv = v[0]; int mi = id[0];
#pragma unroll
        for (int s = 32; s > 0; s >>= 1) {
            float ov = __shfl_xor(mv, s); int oi = __shfl_xor(mi, s);
            if (ov > mv || (ov == mv && oi < mi)) { mv = ov; mi = oi; }
        }
        if (v[0] == mv && id[0] == mi) {
#pragma unroll
            for (int j = 0; j < 15; ++j) { v[j] = v[j + 1]; id[j] = id[j + 1]; }
            v[15] = -FLT_MAX; id[15] = 0x7fffffff;
        }
        if (lane == 0) { sv[wid * 16 + rr] = mv; si[wid * 16 + rr] = mi; }
    }
    __syncthreads();

    if (wid == 0) {
        float lv = sv[lane]; int li = si[lane];
        float sel_v = -FLT_MAX; int sel_i = 0;
        for (int rr = 0; rr < NRET; ++rr) {
            float mv = lv; int mi = li;
#pragma unroll
            for (int s = 32; s > 0; s >>= 1) {
                float ov = __shfl_xor(mv, s); int oi = __shfl_xor(mi, s);
                if (ov > mv || (ov == mv && oi < mi)) { mv = ov; mi = oi; }
            }
            if (lv == mv && li == mi) { lv = -FLT_MAX; li = 0x7fffffff; }
            if (lane == rr) { sel_v = mv; sel_i = mi; }
        }

        // softmax over the 16 (lane 0 holds the max: rounds are descending)
        float m0 = __shfl(sel_v, 0);
        float e = (lane < NRET) ? expf(sel_v - m0) : 0.0f;
        float denom = wave_sum(e);

        float acc0 = 0.f, acc1 = 0.f;
        for (int rr = 0; rr < NRET; ++rr) {
            float ar = __shfl(e, rr) / denom;
            int   ir = __shfl(sel_i, rr);
            const float* vr = values + (size_t)ir * VALUE_DIM;
            acc0 += ar * vr[lane];
            acc1 += ar * vr[lane + 64];
        }
        out[lane]      = acc0;
        out[lane + 64] = acc1;
    }
}

extern "C" void kernel_launch(void* const* d_in, const int* in_sizes, int n_in,
                              void* d_out, int out_size, void* d_ws, size_t ws_size,
                              hipStream_t stream) {
    const float* query  = (const float*)d_in[0];
    const float* W1     = (const float*)d_in[1];
    const float* b1     = (const float*)d_in[2];
    const float* W2     = (const float*)d_in[3];
    const float* b2     = (const float*)d_in[4];
    const float* gamma  = (const float*)d_in[5];
    const float* beta   = (const float*)d_in[6];
    const float* keys   = (const float*)d_in[7];
    const float* values = (const float*)d_in[8];
    float* out = (float*)d_out;

    float* ws = (float*)d_ws;
    float* h1     = ws;                         // 512
    float* h2     = ws + 512;                   // 512
    float* qn     = ws + 1024;                  // 512
    float* sims   = ws + 2048;                  // 500000 floats (~2 MB)
    float* cand_v = ws + 2048 + CAPACITY;       // 512
    int*   cand_i = (int*)(cand_v + TKBLKS * NRET);

    matvec512<true ><<<128, 256, 0, stream>>>(W1, query, b1, h1);
    matvec512<false><<<128, 256, 0, stream>>>(W2, h1, b2, h2);
    ln_l2norm<<<1, 512, 0, stream>>>(h2, gamma, beta, qn);
    sim_all<<<SIMBLKS, 256, 0, stream>>>(keys, qn, sims);
    topk_stage1<<<TKBLKS, 256, 0, stream>>>(sims, cand_v, cand_i);
    merge_out<<<1, 256, 0, stream>>>(cand_v, cand_i, values, out);
}

// Round 7
// 264.578 us; speedup vs baseline: 1.9051x; 1.3805x over previous
//
#include <hip/hip_runtime.h>
#include <hip/hip_bf16.h>
#include <float.h>
#include <math.h>

#define KEY_DIM   512
#define VALUE_DIM 128
#define CAPACITY  500000
#define NRET      16

#define NBLKS     512                      // 2 blocks/CU, all resident
#define NTILES    (CAPACITY / 16)          // 31250 tiles of 16 rows

#define AS3 __attribute__((address_space(3)))
#define AS1 __attribute__((address_space(1)))

__device__ __forceinline__ float wave_sum(float x) {
#pragma unroll
    for (int s = 32; s > 0; s >>= 1) x += __shfl_xor(x, s);
    return x;
}

// ---------------- Kernel 1a/1b: y[r] = act(dot(W[r,:], x) + b[r]) ----------
template <bool SILU>
__global__ __launch_bounds__(256) void matvec512(
        const float* __restrict__ W, const float* __restrict__ x,
        const float* __restrict__ b, float* __restrict__ y) {
    const int wid  = threadIdx.x >> 6;
    const int lane = threadIdx.x & 63;
    const int r = blockIdx.x * 4 + wid;          // 0..511

    const float4* Wr = (const float4*)(W + (size_t)r * KEY_DIM);
    const float4* xv = (const float4*)x;

    float4 w0 = Wr[lane], w1 = Wr[lane + 64];
    float4 x0 = xv[lane], x1 = xv[lane + 64];

    float dot = w0.x * x0.x + w0.y * x0.y + w0.z * x0.z + w0.w * x0.w
              + w1.x * x1.x + w1.y * x1.y + w1.z * x1.z + w1.w * x1.w;
    dot = wave_sum(dot);

    if (lane == 0) {
        float v = dot + b[r];
        if (SILU) v = v / (1.0f + expf(-v));     // silu = x*sigmoid(x)
        y[r] = v;
    }
}

// ---------------- Kernel 1c: LayerNorm + l2-normalize -> qn[512] -----------
__global__ __launch_bounds__(512) void ln_l2norm(
        const float* __restrict__ h, const float* __restrict__ gamma,
        const float* __restrict__ beta, float* __restrict__ qn) {
    __shared__ float s1[8], s2[8];
    const int t = threadIdx.x;                   // 512 threads = 8 waves
    const int wid = t >> 6, lane = t & 63;

    float x = h[t];
    float a = x, bb = x * x;
#pragma unroll
    for (int s = 32; s > 0; s >>= 1) { a += __shfl_xor(a, s); bb += __shfl_xor(bb, s); }
    if (lane == 0) { s1[wid] = a; s2[wid] = bb; }
    __syncthreads();

    float suma = 0.f, sumb = 0.f;
#pragma unroll
    for (int i = 0; i < 8; ++i) { suma += s1[i]; sumb += s2[i]; }
    float mu  = suma * (1.0f / KEY_DIM);
    float var = sumb * (1.0f / KEY_DIM) - mu * mu;      // biased, like torch LN
    float ln  = (x - mu) / sqrtf(var + 1e-5f) * gamma[t] + beta[t];

    float c = wave_sum(ln * ln);
    __syncthreads();
    if (lane == 0) s1[wid] = c;
    __syncthreads();
    float ss = 0.f;
#pragma unroll
    for (int i = 0; i < 8; ++i) ss += s1[i];
    float n = fmaxf(sqrtf(ss), 1e-12f);
    qn[t] = ln / n;
}

// ---------------- Kernel 2: wave-private LDS-staged cosine sim -------------
// Each wave stages ITS OWN 4 rows/tile via global_load_lds (coalesced 1KB
// instructions) into a wave-private double buffer and computes them itself:
// NO barriers in the loop; ordering is wave-local inline-asm vmcnt(8) only.
// LDS store is linear (HW); bank spread comes from a SOURCE-side cell
// permutation: physical cell p in a row holds logical cell
// L(p) = 8*(p>>3) + (((p&7)-(p>>3))&7). Lane m reads its logical cells 8m+j
// at physical 8m+((j+m)&7) -> per-j banks spread across all 8 groups
// (structural b128 floor), while q-fragment indexing qr[j] stays STATIC.
__global__ __launch_bounds__(256) void sim_topk(
        const float* __restrict__ keys, const float* __restrict__ qn,
        float* __restrict__ cand_v, int* __restrict__ cand_i) {
    __shared__ float kl[2][16][KEY_DIM];             // 64 KB: [buf][row][col]
    __shared__ float bv[64];
    __shared__ int   bi[64];

    const int tid  = threadIdx.x;
    const int w    = tid >> 6;
    const int lane = tid & 63;
    const int m    = lane & 15;                      // col-slice in quarter
    const int qd   = lane >> 4;                      // row within wave's 4
    const int bid  = blockIdx.x;
    const int nt   = (NTILES - bid + NBLKS - 1) / NBLKS;   // 61 or 62

    // q fragment: logical cells 8m..8m+7 (32 floats)
    float4 qr[8];
    {
        const float4* q4 = (const float4*)qn;
#pragma unroll
        for (int j = 0; j < 8; ++j) qr[j] = q4[8 * m + j];
    }

    // per-lane source byte offsets within a row for the two 1KB halves
    int srcoff0, srcoff1;
    {
        int p0 = lane,      g0 = p0 >> 3, s0 = p0 & 7;
        int p1 = 64 + lane, g1 = p1 >> 3, s1 = p1 & 7;
        srcoff0 = (8 * g0 + ((s0 - g0) & 7)) * 16;
        srcoff1 = (8 * g1 + ((s1 - g1) & 7)) * 16;
    }
    // per-lane read byte offsets (within own row) for j=0..7
    int roff[8];
#pragma unroll
    for (int j = 0; j < 8; ++j) roff[j] = (8 * m + ((j + m) & 7)) * 16;

    // wave-uniform top-16
    float v[16]; int id[16];
#pragma unroll
    for (int j = 0; j < 16; ++j) { v[j] = -FLT_MAX; id[j] = 0x7fffffff; }

    // ---- stage: wave w stages rows 4w..4w+3 of tile g into buf (8 loads) --
    auto stage = [&](int g, int buf) {
#pragma unroll
        for (int i = 0; i < 8; ++i) {
            const int rl  = i >> 1;                  // 0..3
            const int h   = i & 1;
            const char* gp = (const char*)(keys + ((size_t)g * 16 + 4 * w + rl) * KEY_DIM)
                             + (h ? srcoff1 : srcoff0);
            float* lp = &kl[buf][4 * w + rl][h * 256];   // wave-uniform base
            __builtin_amdgcn_global_load_lds((const AS1 float*)gp, (AS3 float*)lp,
                                             16, 0, 0);
        }
    };

    // ---- compute: wave processes its 4 rows of tile g from buf ------------
    auto compute = [&](int g, int buf) {
        const char* rowbase = (const char*)&kl[buf][4 * w + qd][0];
        float dot = 0.f, ss = 0.f;
#pragma unroll
        for (int j = 0; j < 8; ++j) {
            float4 k = *(const float4*)(rowbase + roff[j]);
            float4 q = qr[j];
            dot += k.x * q.x + k.y * q.y + k.z * q.z + k.w * q.w;
            ss  += k.x * k.x + k.y * k.y + k.z * k.z + k.w * k.w;
        }
        // 16-lane segment reduce (stays within each quarter)
#pragma unroll
        for (int s = 8; s > 0; s >>= 1) {
            dot += __shfl_xor(dot, s);
            ss  += __shfl_xor(ss, s);
        }
        float sim = dot / fmaxf(sqrtf(ss), 1e-12f);  // all lanes of quarter
#pragma unroll
        for (int q = 0; q < 4; ++q) {
            float sq = __shfl(sim, q * 16);          // wave-uniform
            if (sq > v[15]) {
                float cv = sq; int ci = g * 16 + w * 4 + q;
#pragma unroll
                for (int jj = 0; jj < 16; ++jj) {
                    if (cv > v[jj]) {
                        float tv = v[jj]; int ti = id[jj];
                        v[jj] = cv; id[jj] = ci; cv = tv; ci = ti;
                    }
                }
            }
        }
    };

    // ---- pipelined main loop (no barriers; wave-local counted vmcnt) ------
    stage(bid, 0);
    stage(bid + NBLKS, 1);

    int t = 0;
#pragma unroll 1
    for (; t < nt - 2; ++t) {
        asm volatile("s_waitcnt vmcnt(8)" ::: "memory");
        __builtin_amdgcn_sched_barrier(0);
        compute(bid + t * NBLKS, t & 1);
        stage(bid + (t + 2) * NBLKS, t & 1);
    }
    asm volatile("s_waitcnt vmcnt(8)" ::: "memory");
    __builtin_amdgcn_sched_barrier(0);
    compute(bid + t * NBLKS, t & 1);
    ++t;
    asm volatile("s_waitcnt vmcnt(0)" ::: "memory");
    __builtin_amdgcn_sched_barrier(0);
    compute(bid + t * NBLKS, t & 1);

    // ---- merge 4 waves' top-16 -> block top-16 ----------------------------
    if (lane == 0) {
#pragma unroll
        for (int j = 0; j < 16; ++j) { bv[w * 16 + j] = v[j]; bi[w * 16 + j] = id[j]; }
    }
    __syncthreads();
    if (w == 0) {
        float lv = bv[lane]; int li = bi[lane];
        for (int rr = 0; rr < NRET; ++rr) {
            float mv = lv; int mi = li;
#pragma unroll
            for (int s = 32; s > 0; s >>= 1) {
                float ov = __shfl_xor(mv, s); int oi = __shfl_xor(mi, s);
                if (ov > mv || (ov == mv && oi < mi)) { mv = ov; mi = oi; }
            }
            if (lane == 0) {
                cand_v[bid * NRET + rr] = mv;
                cand_i[bid * NRET + rr] = mi;
            }
            if (lv == mv && li == mi) { lv = -FLT_MAX; li = 0x7fffffff; }
        }
    }
}

// ---------------- Kernel 3: final top-16 + softmax + gather ----------------
__global__ __launch_bounds__(256) void merge_out(
        const float* __restrict__ cand_v, const int* __restrict__ cand_i,
        const float* __restrict__ values, float* __restrict__ out) {
    const int tid  = threadIdx.x;
    const int wid  = tid >> 6;
    const int lane = tid & 63;
    const int M4 = (NBLKS * NRET) / 4;           // 2048 float4 groups

    float v[16]; int id[16];
#pragma unroll
    for (int j = 0; j < 16; ++j) { v[j] = -FLT_MAX; id[j] = 0x7fffffff; }

    const float4* cv4 = (const float4*)cand_v;
    const int4*   ci4 = (const int4*)cand_i;
    for (int c = tid; c < M4; c += 256) {        // 8 iterations
        float4 cv = cv4[c]; int4 ci = ci4[c];
        float cvs[4] = {cv.x, cv.y, cv.z, cv.w};
        int   cis[4] = {ci.x, ci.y, ci.z, ci.w};
#pragma unroll
        for (int u = 0; u < 4; ++u) {
            float cu = cvs[u]; int iu = cis[u];
            if (cu > v[15]) {
#pragma unroll
                for (int j = 0; j < 16; ++j) {
                    if (cu > v[j]) {
                        float tv = v[j]; int ti = id[j];
                        v[j] = cu; id[j] = iu; cu = tv; iu = ti;
                    }
                }
            }
        }
    }

    __shared__ float sv[64];
    __shared__ int   si[64];
    for (int rr = 0; rr < NRET; ++rr) {
        float mv = v[0]; int mi = id[0];
#pragma unroll
        for (int s = 32; s > 0; s >>= 1) {
            float ov = __shfl_xor(mv, s); int oi = __shfl_xor(mi, s);
            if (ov > mv || (ov == mv && oi < mi)) { mv = ov; mi = oi; }
        }
        if (v[0] == mv && id[0] == mi) {
#pragma unroll
            for (int j = 0; j < 15; ++j) { v[j] = v[j + 1]; id[j] = id[j + 1]; }
            v[15] = -FLT_MAX; id[15] = 0x7fffffff;
        }
        if (lane == 0) { sv[wid * 16 + rr] = mv; si[wid * 16 + rr] = mi; }
    }
    __syncthreads();

    if (wid == 0) {
        float lv = sv[lane]; int li = si[lane];
        float sel_v = -FLT_MAX; int sel_i = 0;
        for (int rr = 0; rr < NRET; ++rr) {
            float mv = lv; int mi = li;
#pragma unroll
            for (int s = 32; s > 0; s >>= 1) {
                float ov = __shfl_xor(mv, s); int oi = __shfl_xor(mi, s);
                if (ov > mv || (ov == mv && oi < mi)) { mv = ov; mi = oi; }
            }
            if (lv == mv && li == mi) { lv = -FLT_MAX; li = 0x7fffffff; }
            if (lane == rr) { sel_v = mv; sel_i = mi; }
        }

        // softmax over the 16 (lane 0 holds the max: rounds are descending)
        float m0 = __shfl(sel_v, 0);
        float e = (lane < NRET) ? expf(sel_v - m0) : 0.0f;
        float denom = wave_sum(e);

        float acc0 = 0.f, acc1 = 0.f;
        for (int rr = 0; rr < NRET; ++rr) {
            float ar = __shfl(e, rr) / denom;
            int   ir = __shfl(sel_i, rr);
            const float* vr = values + (size_t)ir * VALUE_DIM;
            acc0 += ar * vr[lane];
            acc1 += ar * vr[lane + 64];
        }
        out[lane]      = acc0;
        out[lane + 64] = acc1;
    }
}

extern "C" void kernel_launch(void* const* d_in, const int* in_sizes, int n_in,
                              void* d_out, int out_size, void* d_ws, size_t ws_size,
                              hipStream_t stream) {
    const float* query  = (const float*)d_in[0];
    const float* W1     = (const float*)d_in[1];
    const float* b1     = (const float*)d_in[2];
    const float* W2     = (const float*)d_in[3];
    const float* b2     = (const float*)d_in[4];
    const float* gamma  = (const float*)d_in[5];
    const float* beta   = (const float*)d_in[6];
    const float* keys   = (const float*)d_in[7];
    const float* values = (const float*)d_in[8];
    float* out = (float*)d_out;

    float* ws = (float*)d_ws;
    float* h1     = ws;                  // 512
    float* h2     = ws + 512;            // 512
    float* qn     = ws + 1024;           // 512
    float* cand_v = ws + 2048;           // NBLKS*16 floats
    int*   cand_i = (int*)(ws + 2048 + NBLKS * NRET);

    matvec512<true ><<<128, 256, 0, stream>>>(W1, query, b1, h1);
    matvec512<false><<<128, 256, 0, stream>>>(W2, h1, b2, h2);
    ln_l2norm<<<1, 512, 0, stream>>>(h2, gamma, beta, qn);
    sim_topk<<<NBLKS, 256, 0, stream>>>(keys, qn, cand_v, cand_i);
    merge_out<<<1, 256, 0, stream>>>(cand_v, cand_i, values, out);
}